// Round 1
// baseline (991.518 us; speedup 1.0000x reference)
//
#include <hip/hip_runtime.h>
#include <cmath>

constexpr int Bq = 8, Lq = 32768, Dq = 64, Nq = 16, NLq = 4;
constexpr int CLq = 128, NCq = 256;           // NCq*CLq == Lq
constexpr int PT = Bq * Lq / 16;              // 16384 position-tiles of 16

typedef _Float16 f16;
typedef _Float16 half4 __attribute__((ext_vector_type(4)));
typedef float f32x4 __attribute__((ext_vector_type(4)));
typedef float f32x2 __attribute__((ext_vector_type(2)));

static __device__ __forceinline__ float sigm(float x) { return 1.0f / (1.0f + __expf(-x)); }
static __device__ __forceinline__ float gelu_t(float x) {
  // jax.nn.gelu approximate=True == x*sigmoid(2*sqrt(2/pi)*(x+0.044715x^3))
  return x * sigm(1.5957691216057308f * fmaf(0.044715f * x * x, x, x));
}

// -------- setup: per (layer,d,n) lambda = exp(dtA), dC2 = 2*C*(lambda-1)/A, lambda^CL --------
__global__ __launch_bounds__(256) void k_setup(
    const float* __restrict__ log_dt, const float* __restrict__ log_A_real,
    const float* __restrict__ A_imag, const float* __restrict__ C_re,
    const float* __restrict__ C_im,
    f32x2* __restrict__ LAM, f32x2* __restrict__ DC2, f32x2* __restrict__ LCL) {
  int idx = blockIdx.x * 256 + threadIdx.x;
  if (idx >= NLq * Dq * Nq) return;
  int di = idx / Nq;  // i*64 + d
  float dt = expf(log_dt[di]);
  float Ar = -expf(log_A_real[idx]);
  float Ai = A_imag[idx];
  float dr = Ar * dt, dmi = Ai * dt;
  float er = expf(dr);
  float lr = er * cosf(dmi), li = er * sinf(dmi);
  float inv = 1.0f / (Ar * Ar + Ai * Ai);
  float e1r = lr - 1.0f, e1i = li;
  float qr = (e1r * Ar + e1i * Ai) * inv;
  float qi = (e1i * Ar - e1r * Ai) * inv;
  float cr = C_re[idx], ci = C_im[idx];
  LAM[idx] = f32x2{lr, li};
  DC2[idx] = f32x2{2.0f * (cr * qr - ci * qi), 2.0f * (cr * qi + ci * qr)};
  float erc = expf(dr * (float)CLq);
  LCL[idx] = f32x2{erc * cosf(dmi * (float)CLq), erc * sinf(dmi * (float)CLq)};
}

// -------- init: x = relu(w_init*in + b_init), write LN stats --------
__global__ __launch_bounds__(256) void k_init(
    const float* __restrict__ inp, const float* __restrict__ w_init,
    const float* __restrict__ b_init, float* __restrict__ X, f32x2* __restrict__ STATS) {
  int lane = threadIdx.x & 63;
  int wv = (blockIdx.x * 256 + threadIdx.x) >> 6;
  int nw = gridDim.x * 4;
  int pl = lane & 15, qh = lane >> 4;
  for (int pt = wv; pt < PT; pt += nw) {
    int pos = pt * 16 + pl;
    float v = inp[pos];
    float s = 0.f, s2 = 0.f;
#pragma unroll
    for (int q = 0; q < 4; q++) {
      int d0 = q * 16 + qh * 4;
      f32x4 w4 = *(const f32x4*)(w_init + d0);
      f32x4 b4 = *(const f32x4*)(b_init + d0);
      f32x4 o;
#pragma unroll
      for (int j = 0; j < 4; j++) {
        float t = fmaf(w4[j], v, b4[j]);
        t = t > 0.f ? t : 0.f;
        o[j] = t; s += t; s2 += t * t;
      }
      *(f32x4*)(X + (size_t)pos * 64 + d0) = o;
    }
    s += __shfl_xor(s, 16); s += __shfl_xor(s, 32);
    s2 += __shfl_xor(s2, 16); s2 += __shfl_xor(s2, 32);
    if (qh == 0) {
      float m = s * (1.0f / 64.0f);
      float var = s2 * (1.0f / 64.0f) - m * m;
      STATS[pos] = f32x2{m, rsqrtf(var + 1e-5f)};
    }
  }
}

// -------- pass1: per-chunk local scan, store end states --------
__global__ __launch_bounds__(256) void k_pass1(
    const float* __restrict__ X, const f32x2* __restrict__ STATS,
    const f32x2* __restrict__ LAM, const float* __restrict__ lnw,
    const float* __restrict__ lnb, f32x2* __restrict__ S) {
  int lane = threadIdx.x & 63;
  int w = blockIdx.x * 4 + (threadIdx.x >> 6);
  int b = w / NCq, c = w % NCq;
  int d = lane;
  float lr[16], li[16];
  const f32x2* lam = LAM + d * Nq;
#pragma unroll
  for (int n = 0; n < 16; n++) { f32x2 t = lam[n]; lr[n] = t.x; li[n] = t.y; }
  float wd = lnw[d], bd = lnb[d];
  float sr[16], si[16];
#pragma unroll
  for (int n = 0; n < 16; n++) { sr[n] = 0.f; si[n] = 0.f; }
  const float* xp = X + ((size_t)b * Lq + (size_t)c * CLq) * 64 + d;
  const f32x2* st = STATS + (b * Lq + c * CLq);
#pragma unroll 4
  for (int l = 0; l < CLq; l++) {
    float x = xp[(size_t)l * 64];
    f32x2 ms = st[l];
    float z = fmaf((x - ms.x) * ms.y, wd, bd);
#pragma unroll
    for (int n = 0; n < 16; n++) {
      float nr = fmaf(lr[n], sr[n], fmaf(-li[n], si[n], z));
      float ni = fmaf(lr[n], si[n], li[n] * sr[n]);
      sr[n] = nr; si[n] = ni;
    }
  }
  f32x2* outp = S + (size_t)((b * NCq + c) * 64 + d) * 16;
#pragma unroll
  for (int n = 0; n < 16; n++) outp[n] = f32x2{sr[n], si[n]};
}

// -------- pass2: sequential combine across chunks; replace S[c] with initial state --------
__global__ __launch_bounds__(256) void k_pass2(f32x2* __restrict__ S, const f32x2* __restrict__ LCL) {
  int tid = blockIdx.x * 256 + threadIdx.x;  // 8192 = B*D*N
  int n = tid & 15, d = (tid >> 4) & 63, b = tid >> 10;
  f32x2 lam = LCL[d * 16 + n];
  float cr = 0.f, ci = 0.f;
  for (int c = 0; c < NCq; c++) {
    int idx = ((b * NCq + c) * 64 + d) * 16 + n;
    f32x2 t = S[idx];
    S[idx] = f32x2{cr, ci};
    float nr = fmaf(lam.x, cr, fmaf(-lam.y, ci, t.x));
    float ni = fmaf(lam.x, ci, fmaf(lam.y, cr, t.y));
    cr = nr; ci = ni;
  }
}

// -------- pass3: rescan with carried init state, y = 2ReSum(dC*s)+Dskip*z, gelu --------
__global__ __launch_bounds__(256) void k_pass3(
    const float* __restrict__ X, const f32x2* __restrict__ STATS, const f32x2* __restrict__ S,
    const f32x2* __restrict__ LAM, const f32x2* __restrict__ DC2,
    const float* __restrict__ lnw, const float* __restrict__ lnb,
    const float* __restrict__ dskip, float* __restrict__ Y) {
  int lane = threadIdx.x & 63;
  int w = blockIdx.x * 4 + (threadIdx.x >> 6);
  int b = w / NCq, c = w % NCq;
  int d = lane;
  float lr[16], li[16], cr2[16], ci2[16];
  const f32x2* lam = LAM + d * 16;
  const f32x2* dc = DC2 + d * 16;
#pragma unroll
  for (int n = 0; n < 16; n++) {
    f32x2 t = lam[n]; lr[n] = t.x; li[n] = t.y;
    f32x2 u = dc[n]; cr2[n] = u.x; ci2[n] = u.y;
  }
  float wd = lnw[d], bd = lnb[d], dk = dskip[d];
  float sr[16], si[16];
  const f32x2* s0 = S + (size_t)((b * NCq + c) * 64 + d) * 16;
#pragma unroll
  for (int n = 0; n < 16; n++) { f32x2 t = s0[n]; sr[n] = t.x; si[n] = t.y; }
  const float* xp = X + ((size_t)b * Lq + (size_t)c * CLq) * 64 + d;
  float* yp = Y + ((size_t)b * Lq + (size_t)c * CLq) * 64 + d;
  const f32x2* st = STATS + (b * Lq + c * CLq);
#pragma unroll 2
  for (int l = 0; l < CLq; l++) {
    float x = xp[(size_t)l * 64];
    f32x2 ms = st[l];
    float z = fmaf((x - ms.x) * ms.y, wd, bd);
    float y = dk * z;
#pragma unroll
    for (int n = 0; n < 16; n++) {
      float nr = fmaf(lr[n], sr[n], fmaf(-li[n], si[n], z));
      float ni = fmaf(lr[n], si[n], li[n] * sr[n]);
      sr[n] = nr; si[n] = ni;
      y = fmaf(cr2[n], nr, fmaf(-ci2[n], ni, y));
    }
    yp[(size_t)l * 64] = gelu_t(y);
  }
}

// -------- glu: u = W(128x64) @ y + b; x += u_a * sigmoid(u_g); write ff-LN stats --------
__global__ __launch_bounds__(256) void k_glu(
    const float* __restrict__ Yb, const float* __restrict__ W, const float* __restrict__ bias,
    float* __restrict__ X, f32x2* __restrict__ STATS) {
  int lane = threadIdx.x & 63;
  int wv = (blockIdx.x * 256 + threadIdx.x) >> 6;
  int nw = gridDim.x * 4;
  int pl = lane & 15, qh = lane >> 4;
  half4 af[8][4];
#pragma unroll
  for (int et = 0; et < 8; et++)
#pragma unroll
    for (int ks = 0; ks < 4; ks++) {
      f32x4 w4 = *(const f32x4*)(W + (et * 16 + pl) * 64 + ks * 16 + qh * 4);
      af[et][ks] = half4{(f16)w4[0], (f16)w4[1], (f16)w4[2], (f16)w4[3]};
    }
  for (int pt = wv; pt < PT; pt += nw) {
    int pos = pt * 16 + pl;
    half4 bf[4];
#pragma unroll
    for (int ks = 0; ks < 4; ks++) {
      f32x4 y4 = *(const f32x4*)(Yb + (size_t)pos * 64 + ks * 16 + qh * 4);
      bf[ks] = half4{(f16)y4[0], (f16)y4[1], (f16)y4[2], (f16)y4[3]};
    }
    f32x4 acc[8];
#pragma unroll
    for (int et = 0; et < 8; et++) acc[et] = *(const f32x4*)(bias + et * 16 + qh * 4);
#pragma unroll
    for (int ks = 0; ks < 4; ks++)
#pragma unroll
      for (int et = 0; et < 8; et++)
        acc[et] = __builtin_amdgcn_mfma_f32_16x16x16f16(af[et][ks], bf[ks], acc[et], 0, 0, 0);
    float s = 0.f, s2 = 0.f;
#pragma unroll
    for (int et = 0; et < 4; et++) {
      f32x4 xv = *(const f32x4*)(X + (size_t)pos * 64 + et * 16 + qh * 4);
#pragma unroll
      for (int r = 0; r < 4; r++) {
        xv[r] += acc[et][r] * sigm(acc[et + 4][r]);
        s += xv[r]; s2 += xv[r] * xv[r];
      }
      *(f32x4*)(X + (size_t)pos * 64 + et * 16 + qh * 4) = xv;
    }
    s += __shfl_xor(s, 16); s += __shfl_xor(s, 32);
    s2 += __shfl_xor(s2, 16); s2 += __shfl_xor(s2, 32);
    if (qh == 0) {
      float m = s * (1.0f / 64.0f);
      float var = s2 * (1.0f / 64.0f) - m * m;
      STATS[pos] = f32x2{m, rsqrtf(var + 1e-5f)};
    }
  }
}

// -------- ff: z=LN(x); h=gelu(W1 z + b1); x += W2 h + b2; write next s4-LN stats --------
__global__ __launch_bounds__(256) void k_ff(
    const float* __restrict__ W1, const float* __restrict__ b1,
    const float* __restrict__ W2, const float* __restrict__ b2,
    const float* __restrict__ lnw, const float* __restrict__ lnb,
    float* __restrict__ X, f32x2* __restrict__ STATS) {
  int lane = threadIdx.x & 63;
  int wv = (blockIdx.x * 256 + threadIdx.x) >> 6;
  int nw = gridDim.x * 4;
  int pl = lane & 15, qh = lane >> 4;
  half4 a1[8][4], a2[4][8];
#pragma unroll
  for (int et = 0; et < 8; et++)
#pragma unroll
    for (int ks = 0; ks < 4; ks++) {
      f32x4 w4 = *(const f32x4*)(W1 + (et * 16 + pl) * 64 + ks * 16 + qh * 4);
      a1[et][ks] = half4{(f16)w4[0], (f16)w4[1], (f16)w4[2], (f16)w4[3]};
    }
#pragma unroll
  for (int dt = 0; dt < 4; dt++)
#pragma unroll
    for (int ks = 0; ks < 8; ks++) {
      f32x4 w4 = *(const f32x4*)(W2 + (dt * 16 + pl) * 128 + ks * 16 + qh * 4);
      a2[dt][ks] = half4{(f16)w4[0], (f16)w4[1], (f16)w4[2], (f16)w4[3]};
    }
  for (int pt = wv; pt < PT; pt += nw) {
    int pos = pt * 16 + pl;
    f32x2 ms = STATS[pos];
    half4 bf[4];
#pragma unroll
    for (int ks = 0; ks < 4; ks++) {
      f32x4 x4 = *(const f32x4*)(X + (size_t)pos * 64 + ks * 16 + qh * 4);
      f32x4 lw = *(const f32x4*)(lnw + ks * 16 + qh * 4);
      f32x4 lb = *(const f32x4*)(lnb + ks * 16 + qh * 4);
      f32x4 z;
#pragma unroll
      for (int j = 0; j < 4; j++) z[j] = fmaf((x4[j] - ms.x) * ms.y, lw[j], lb[j]);
      bf[ks] = half4{(f16)z[0], (f16)z[1], (f16)z[2], (f16)z[3]};
    }
    f32x4 acc1[8];
#pragma unroll
    for (int et = 0; et < 8; et++) acc1[et] = *(const f32x4*)(b1 + et * 16 + qh * 4);
#pragma unroll
    for (int ks = 0; ks < 4; ks++)
#pragma unroll
      for (int et = 0; et < 8; et++)
        acc1[et] = __builtin_amdgcn_mfma_f32_16x16x16f16(a1[et][ks], bf[ks], acc1[et], 0, 0, 0);
    half4 h2[8];
#pragma unroll
    for (int et = 0; et < 8; et++)
      h2[et] = half4{(f16)gelu_t(acc1[et][0]), (f16)gelu_t(acc1[et][1]),
                     (f16)gelu_t(acc1[et][2]), (f16)gelu_t(acc1[et][3])};
    f32x4 acc2[4];
#pragma unroll
    for (int dt = 0; dt < 4; dt++) acc2[dt] = *(const f32x4*)(b2 + dt * 16 + qh * 4);
#pragma unroll
    for (int ks = 0; ks < 8; ks++)
#pragma unroll
      for (int dt = 0; dt < 4; dt++)
        acc2[dt] = __builtin_amdgcn_mfma_f32_16x16x16f16(a2[dt][ks], h2[ks], acc2[dt], 0, 0, 0);
    float s = 0.f, s2 = 0.f;
#pragma unroll
    for (int dt = 0; dt < 4; dt++) {
      f32x4 xv = *(const f32x4*)(X + (size_t)pos * 64 + dt * 16 + qh * 4);
#pragma unroll
      for (int r = 0; r < 4; r++) {
        xv[r] += acc2[dt][r];
        s += xv[r]; s2 += xv[r] * xv[r];
      }
      *(f32x4*)(X + (size_t)pos * 64 + dt * 16 + qh * 4) = xv;
    }
    s += __shfl_xor(s, 16); s += __shfl_xor(s, 32);
    s2 += __shfl_xor(s2, 16); s2 += __shfl_xor(s2, 32);
    if (qh == 0) {
      float m = s * (1.0f / 64.0f);
      float var = s2 * (1.0f / 64.0f) - m * m;
      STATS[pos] = f32x2{m, rsqrtf(var + 1e-5f)};
    }
  }
}

// -------- head: z=LN(x,norm); r=relu(Wf z + bf); out = wz.r + bz --------
__global__ __launch_bounds__(256) void k_head(
    const float* __restrict__ X, const f32x2* __restrict__ STATS,
    const float* __restrict__ nw_, const float* __restrict__ nb_,
    const float* __restrict__ Wf, const float* __restrict__ bfb,
    const float* __restrict__ wz, const float* __restrict__ bz,
    float* __restrict__ outp) {
  int lane = threadIdx.x & 63;
  int wv = (blockIdx.x * 256 + threadIdx.x) >> 6;
  int nwv = gridDim.x * 4;
  int pl = lane & 15, qh = lane >> 4;
  half4 af[4][4];
#pragma unroll
  for (int et = 0; et < 4; et++)
#pragma unroll
    for (int ks = 0; ks < 4; ks++) {
      f32x4 w4 = *(const f32x4*)(Wf + (et * 16 + pl) * 64 + ks * 16 + qh * 4);
      af[et][ks] = half4{(f16)w4[0], (f16)w4[1], (f16)w4[2], (f16)w4[3]};
    }
  float bz0 = bz[0];
  for (int pt = wv; pt < PT; pt += nwv) {
    int pos = pt * 16 + pl;
    f32x2 ms = STATS[pos];
    half4 bf[4];
#pragma unroll
    for (int ks = 0; ks < 4; ks++) {
      f32x4 x4 = *(const f32x4*)(X + (size_t)pos * 64 + ks * 16 + qh * 4);
      f32x4 lw = *(const f32x4*)(nw_ + ks * 16 + qh * 4);
      f32x4 lb = *(const f32x4*)(nb_ + ks * 16 + qh * 4);
      f32x4 z;
#pragma unroll
      for (int j = 0; j < 4; j++) z[j] = fmaf((x4[j] - ms.x) * ms.y, lw[j], lb[j]);
      bf[ks] = half4{(f16)z[0], (f16)z[1], (f16)z[2], (f16)z[3]};
    }
    f32x4 acc[4];
#pragma unroll
    for (int et = 0; et < 4; et++) acc[et] = *(const f32x4*)(bfb + et * 16 + qh * 4);
#pragma unroll
    for (int ks = 0; ks < 4; ks++)
#pragma unroll
      for (int et = 0; et < 4; et++)
        acc[et] = __builtin_amdgcn_mfma_f32_16x16x16f16(af[et][ks], bf[ks], acc[et], 0, 0, 0);
    float o = 0.f;
#pragma unroll
    for (int et = 0; et < 4; et++) {
      f32x4 wzv = *(const f32x4*)(wz + et * 16 + qh * 4);
#pragma unroll
      for (int r = 0; r < 4; r++) {
        float rv = acc[et][r];
        rv = rv > 0.f ? rv : 0.f;
        o = fmaf(wzv[r], rv, o);
      }
    }
    o += __shfl_xor(o, 16); o += __shfl_xor(o, 32);
    if (qh == 0) outp[pos] = o + bz0;
  }
}

extern "C" void kernel_launch(void* const* d_in, const int* in_sizes, int n_in,
                              void* d_out, int out_size, void* d_ws, size_t ws_size,
                              hipStream_t stream) {
  (void)in_sizes; (void)n_in; (void)out_size; (void)ws_size;
  const float* inputs   = (const float*)d_in[0];
  const float* w_init   = (const float*)d_in[1];
  const float* b_init   = (const float*)d_in[2];
  const float* s4_ln_w  = (const float*)d_in[3];
  const float* s4_ln_b  = (const float*)d_in[4];
  const float* log_dt   = (const float*)d_in[5];
  const float* log_A    = (const float*)d_in[6];
  const float* A_imag   = (const float*)d_in[7];
  const float* C_re     = (const float*)d_in[8];
  const float* C_im     = (const float*)d_in[9];
  const float* D_skip   = (const float*)d_in[10];
  const float* s4_out_w = (const float*)d_in[11];
  const float* s4_out_b = (const float*)d_in[12];
  const float* ff_ln_w  = (const float*)d_in[13];
  const float* ff_ln_b  = (const float*)d_in[14];
  const float* ff_w1    = (const float*)d_in[15];
  const float* ff_b1    = (const float*)d_in[16];
  const float* ff_w2    = (const float*)d_in[17];
  const float* ff_b2    = (const float*)d_in[18];
  const float* norm_w   = (const float*)d_in[19];
  const float* norm_b   = (const float*)d_in[20];
  const float* w_final1 = (const float*)d_in[21];
  const float* b_final1 = (const float*)d_in[22];
  const float* w_zero   = (const float*)d_in[23];
  const float* b_zero   = (const float*)d_in[24];

  float* ws = (float*)d_ws;
  float* X = ws;                                        // B*L*64
  float* Y = X + (size_t)Bq * Lq * 64;                  // B*L*64
  f32x2* S = (f32x2*)(Y + (size_t)Bq * Lq * 64);        // B*NC*64*16
  f32x2* STATS = S + (size_t)Bq * NCq * 64 * 16;        // B*L
  f32x2* LAM = STATS + (size_t)Bq * Lq;                 // NL*64*16
  f32x2* DC2 = LAM + NLq * Dq * Nq;
  f32x2* LCL = DC2 + NLq * Dq * Nq;

  k_setup<<<16, 256, 0, stream>>>(log_dt, log_A, A_imag, C_re, C_im, LAM, DC2, LCL);
  k_init<<<2048, 256, 0, stream>>>(inputs, w_init, b_init, X, STATS);
  for (int i = 0; i < NLq; i++) {
    k_pass1<<<Bq * NCq / 4, 256, 0, stream>>>(X, STATS, LAM + i * Dq * Nq,
                                              s4_ln_w + i * Dq, s4_ln_b + i * Dq, S);
    k_pass2<<<Bq * Dq * Nq / 256, 256, 0, stream>>>(S, LCL + i * Dq * Nq);
    k_pass3<<<Bq * NCq / 4, 256, 0, stream>>>(X, STATS, S, LAM + i * Dq * Nq, DC2 + i * Dq * Nq,
                                              s4_ln_w + i * Dq, s4_ln_b + i * Dq,
                                              D_skip + i * Dq, Y);
    k_glu<<<1024, 256, 0, stream>>>(Y, s4_out_w + i * 128 * 64, s4_out_b + i * 128, X, STATS);
    k_ff<<<1024, 256, 0, stream>>>(ff_w1 + i * 128 * 64, ff_b1 + i * 128,
                                   ff_w2 + i * 64 * 128, ff_b2 + i * 64,
                                   ff_ln_w + i * Dq, ff_ln_b + i * Dq, X, STATS);
  }
  k_head<<<1024, 256, 0, stream>>>(X, STATS, norm_w, norm_b, w_final1, b_final1,
                                   w_zero, b_zero, (float*)d_out);
}